// Round 13
// baseline (146.451 us; speedup 1.0000x reference)
//
#include <hip/hip_runtime.h>
#include <cstddef>
#include <cstdint>

// B=8192, T=512, I=4, H=32, O=4 — 2-layer tanh RNN + linear head, fp32 I/O.
constexpr int kB = 8192, kT = 512, kI = 4, kH = 32, kO = 4;

typedef _Float16 f16x8 __attribute__((ext_vector_type(8)));
typedef float    f32x4 __attribute__((ext_vector_type(4)));

#define MFMA(a, b, c) __builtin_amdgcn_mfma_f32_16x16x32_f16((a), (b), (c), 0, 0, 0)

// Barrier waiting on LDS ops only (global loads/stores stay in flight).
__device__ __forceinline__ void bar_lds() {
    asm volatile("s_waitcnt lgkmcnt(0)" ::: "memory");
    __builtin_amdgcn_s_barrier();
    __builtin_amdgcn_sched_barrier(0);
}

__device__ __forceinline__ float fast_tanh(float x) {
    // tanh(x) = 1 - 2/(e^{2x}+1); exp2-based, 5 ops (lowest issue), rel err ~1e-6
    float e = __builtin_amdgcn_exp2f(x * 2.8853900817779268f);
    return 1.0f - 2.0f * __builtin_amdgcn_rcpf(e + 1.0f);
}

__device__ __forceinline__ float4 ld4(const float* p) { return *(const float4*)p; }

// A/B fragment from two float4s: elems 0-3 = k {4g..4g+3}, 4-7 = k {16+4g..}.
__device__ __forceinline__ f16x8 pack_frag(float4 lo, float4 hi) {
    f16x8 r;
    r[0] = (_Float16)lo.x; r[1] = (_Float16)lo.y;
    r[2] = (_Float16)lo.z; r[3] = (_Float16)lo.w;
    r[4] = (_Float16)hi.x; r[5] = (_Float16)hi.y;
    r[6] = (_Float16)hi.z; r[7] = (_Float16)hi.w;
    return r;
}

// D-tile regs -> next-step B k-slots; pure per-lane (4x v_cvt_pkrtz).
__device__ __forceinline__ f16x8 pack_state(f32x4 a, f32x4 b) {
    union { f16x8 v; uint32_t u[4]; } r;
    r.u[0] = __builtin_bit_cast(uint32_t, __builtin_amdgcn_cvt_pkrtz(a[0], a[1]));
    r.u[1] = __builtin_bit_cast(uint32_t, __builtin_amdgcn_cvt_pkrtz(a[2], a[3]));
    r.u[2] = __builtin_bit_cast(uint32_t, __builtin_amdgcn_cvt_pkrtz(b[0], b[1]));
    r.u[3] = __builtin_bit_cast(uint32_t, __builtin_amdgcn_cvt_pkrtz(b[2], b[3]));
    return r.v;
}

// x[t] as B-fragment (k=0..3 live on lane-group 0 only).
__device__ __forceinline__ f16x8 bxpack(float4 xn, bool g0) {
    union { f16x8 v; uint32_t u[4]; } bx;
    bx.u[0] = g0 ? __builtin_bit_cast(uint32_t, __builtin_amdgcn_cvt_pkrtz(xn.x, xn.y)) : 0u;
    bx.u[1] = g0 ? __builtin_bit_cast(uint32_t, __builtin_amdgcn_cvt_pkrtz(xn.z, xn.w)) : 0u;
    bx.u[2] = 0u; bx.u[3] = 0u;
    return bx.v;
}

// Epoch-ring pipeline, 3 waves per 16-batch tile, ONE barrier per 8 steps.
//   A (wave0): full L0 in registers. Chain: Bh0 -> 2 par MFMA -> tanh -> pack.
//              xc[i+1] precomputed off-chain; x loaded one epoch ahead.
//   B (wave1): full L1. p[u] = MFMA(W_ih1, h0[u], b1) precomputed one step
//              ahead from a PREFETCHED ring read, so the chain is exactly
//              Bh1 -> MFMA(W_hh1, Bh1, C=p) -> tanh -> pack. (R11's flaws —
//              in-step ds_read + in-step p — both moved off-chain.)
//   D (wave2): head + store only, 2-epoch lag via h1 ring (off everyone's chain).
// Epoch parities: A writes h0 ring (g&1); B reads (g-1)&1, writes h1 (g-1)&1;
// D reads (g-2)&1 — disjoint; slot reuse separated by >=2 barriers.
// Math composition identical to R8 -> absmax must stay exactly 0.00390625.
__global__ __launch_bounds__(192, 2) void rnn2_ring3(
    const float* __restrict__ X,
    const float* __restrict__ W_ih0, const float* __restrict__ W_hh0,
    const float* __restrict__ b_ih0, const float* __restrict__ b_hh0,
    const float* __restrict__ W_ih1, const float* __restrict__ W_hh1,
    const float* __restrict__ b_ih1, const float* __restrict__ b_hh1,
    const float* __restrict__ W_ll, const float* __restrict__ b_ll,
    float* __restrict__ out)
{
    const int  tid = threadIdx.x;
    const int  wid = tid >> 6;       // 0=A(L0) 1=B(L1) 2=D(head)
    const int  l   = tid & 63;
    const int  c   = l & 15;         // batch col within tile / A row m
    const int  g   = l >> 4;         // k-group
    const bool g0  = (g == 0);
    const int  b   = blockIdx.x * 16 + c;
    const int  k0  = 4 * g;

    __shared__ uint4 ring0[16][64];  // h0 fragments, 2 epochs deep
    __shared__ uint4 ring1[16][64];  // h1 fragments, 2 epochs deep

    const float4 z4 = make_float4(0.f, 0.f, 0.f, 0.f);
    union { f16x8 v; uint32_t u[4]; } zz;
    zz.u[0] = zz.u[1] = zz.u[2] = zz.u[3] = 0u;

    constexpr int EP = 8;            // steps per epoch
    constexpr int NE = kT / EP;      // 64 real epochs
    // global phases: A active g<NE; B active 1<=g<=NE; D active 2<=g<=NE+1

    if (wid == 0) {
        // ================= A: layer 0, h0 in registers =================
        const float* wp = W_hh0 + c * kH;
        const f16x8 Ahh0 = pack_frag(ld4(wp + k0), ld4(wp + 16 + k0));
        wp = W_hh0 + (c + 16) * kH;
        const f16x8 Ahh1 = pack_frag(ld4(wp + k0), ld4(wp + 16 + k0));
        const f16x8 Aih0 = pack_frag(g0 ? ld4(W_ih0 + c * kI) : z4, z4);
        const f16x8 Aih1 = pack_frag(g0 ? ld4(W_ih0 + (c + 16) * kI) : z4, z4);
        f32x4 bias0, bias1;
#pragma unroll
        for (int r = 0; r < 4; ++r) {
            bias0[r] = b_ih0[k0 + r]      + b_hh0[k0 + r];
            bias1[r] = b_ih0[16 + k0 + r] + b_hh0[16 + k0 + r];
        }

        const float* xp = X + (size_t)b * (kT * kI);
        f16x8 Bh0 = zz.v;
        f32x4 xc0, xc1;

        float4 xbuf[EP];
#pragma unroll
        for (int u = 0; u < EP; ++u) xbuf[u] = ld4(xp + (1 + u) * kI);
        {
            f16x8 bx = bxpack(ld4(xp), g0);
            xc0 = MFMA(Aih0, bx, bias0);
            xc1 = MFMA(Aih1, bx, bias1);
        }

        for (int e = 0; e < NE + 2; ++e) {
            if (e < NE) {
                float4 xn[EP];
#pragma unroll
                for (int u = 0; u < EP; ++u) {
                    int idx = EP * (e + 1) + 1 + u;
                    idx = idx < kT ? idx : (kT - 1);
                    xn[u] = ld4(xp + idx * kI);
                }
                const int sb = (e & 1) * EP;
#pragma unroll
                for (int u = 0; u < EP; ++u) {
                    f16x8 bx = bxpack(xbuf[u], g0);
                    f32x4 a0 = MFMA(Ahh0, Bh0, xc0);
                    f32x4 a1 = MFMA(Ahh1, Bh0, xc1);
                    xc0 = MFMA(Aih0, bx, bias0);   // xc[i+1], off-chain
                    xc1 = MFMA(Aih1, bx, bias1);
                    f32x4 t0, t1;
#pragma unroll
                    for (int r = 0; r < 4; ++r) { t0[r] = fast_tanh(a0[r]); t1[r] = fast_tanh(a1[r]); }
                    Bh0 = pack_state(t0, t1);
                    ring0[sb + u][l] = __builtin_bit_cast(uint4, Bh0);
                }
#pragma unroll
                for (int u = 0; u < EP; ++u) xbuf[u] = xn[u];
            }
            bar_lds();
        }
    } else if (wid == 1) {
        // ================= B: layer 1, h1 in registers =================
        const float* wp = W_ih1 + c * kH;
        const f16x8 Bih0 = pack_frag(ld4(wp + k0), ld4(wp + 16 + k0));
        wp = W_ih1 + (c + 16) * kH;
        const f16x8 Bih1 = pack_frag(ld4(wp + k0), ld4(wp + 16 + k0));
        wp = W_hh1 + c * kH;
        const f16x8 Bhh0 = pack_frag(ld4(wp + k0), ld4(wp + 16 + k0));
        wp = W_hh1 + (c + 16) * kH;
        const f16x8 Bhh1 = pack_frag(ld4(wp + k0), ld4(wp + 16 + k0));
        f32x4 bias1_0, bias1_1;
#pragma unroll
        for (int r = 0; r < 4; ++r) {
            bias1_0[r] = b_ih1[k0 + r]      + b_hh1[k0 + r];
            bias1_1[r] = b_ih1[16 + k0 + r] + b_hh1[16 + k0 + r];
        }

        f16x8 Bh1 = zz.v;

        for (int e = 0; e < NE + 2; ++e) {
            if (e >= 1 && e <= NE) {
                const int pp = ((e - 1) & 1) * EP;   // h0 slots, epoch e-1
                // prologue: first h0 read + p[0] (only per-epoch exposed read)
                f16x8 H = __builtin_bit_cast(f16x8, ring0[pp + 0][l]);
                f32x4 p0 = MFMA(Bih0, H, bias1_0);
                f32x4 p1 = MFMA(Bih1, H, bias1_1);
#pragma unroll
                for (int u = 0; u < EP; ++u) {
                    f16x8 Hn;
                    if (u < EP - 1)   // prefetch next h0 (off-chain)
                        Hn = __builtin_bit_cast(f16x8, ring0[pp + u + 1][l]);
                    // chain: exactly one MFMA + tanh + pack
                    f32x4 q0 = MFMA(Bhh0, Bh1, p0);
                    f32x4 q1 = MFMA(Bhh1, Bh1, p1);
                    f32x4 t0, t1;
#pragma unroll
                    for (int r = 0; r < 4; ++r) { t0[r] = fast_tanh(q0[r]); t1[r] = fast_tanh(q1[r]); }
                    Bh1 = pack_state(t0, t1);
                    ring1[pp + u][l] = __builtin_bit_cast(uint4, Bh1);
                    if (u < EP - 1) {   // p for next step (off-chain)
                        p0 = MFMA(Bih0, Hn, bias1_0);
                        p1 = MFMA(Bih1, Hn, bias1_1);
                    }
                }
            }
            bar_lds();
        }
    } else {
        // ================= D: head + store =================
        const f16x8 All = (c < kO)
            ? pack_frag(ld4(W_ll + c * kH + k0), ld4(W_ll + c * kH + 16 + k0))
            : pack_frag(z4, z4);
        f32x4 biasll;
#pragma unroll
        for (int r = 0; r < 4; ++r) biasll[r] = g0 ? b_ll[r] : 0.f;
        float* op = out + (size_t)b * (kT * kO);

        for (int e = 0; e < NE + 2; ++e) {
            if (e >= 2) {
                const int rr = ((e - 2) & 1) * EP;   // h1 slots, epoch e-2
                const int j0 = EP * (e - 2);
                f16x8 H1 = __builtin_bit_cast(f16x8, ring1[rr + 0][l]);
#pragma unroll
                for (int u = 0; u < EP; ++u) {
                    f16x8 Hn;
                    if (u < EP - 1)
                        Hn = __builtin_bit_cast(f16x8, ring1[rr + u + 1][l]);
                    f32x4 o = MFMA(All, H1, biasll);
                    if (g0) *(float4*)(op + (size_t)(j0 + u) * kO) =
                        make_float4(o[0], o[1], o[2], o[3]);
                    H1 = Hn;
                }
            }
            bar_lds();
        }
    }
}

extern "C" void kernel_launch(void* const* d_in, const int* in_sizes, int n_in,
                              void* d_out, int out_size, void* d_ws, size_t ws_size,
                              hipStream_t stream) {
    const float* X     = (const float*)d_in[0];
    const float* W_ih0 = (const float*)d_in[1];
    const float* W_hh0 = (const float*)d_in[2];
    const float* b_ih0 = (const float*)d_in[3];
    const float* b_hh0 = (const float*)d_in[4];
    const float* W_ih1 = (const float*)d_in[5];
    const float* W_hh1 = (const float*)d_in[6];
    const float* b_ih1 = (const float*)d_in[7];
    const float* b_hh1 = (const float*)d_in[8];
    const float* W_ll  = (const float*)d_in[9];
    const float* b_ll  = (const float*)d_in[10];
    float* out = (float*)d_out;

    rnn2_ring3<<<dim3(kB / 16), dim3(192), 0, stream>>>(
        X, W_ih0, W_hh0, b_ih0, b_hh0, W_ih1, W_hh1, b_ih1, b_hh1, W_ll, b_ll, out);
}